// Round 10
// baseline (61.304 us; speedup 1.0000x reference)
//
#include <hip/hip_runtime.h>
#include <stdint.h>

#define GLOBAL_AS __attribute__((address_space(1)))
#define LDS_AS    __attribute__((address_space(3)))

typedef __attribute__((ext_vector_type(4))) float f32x4;

constexpr int N  = 4096;   // B*P rows
constexpr int DK = 512;    // feature dim (bytes per row in fp8)
constexpr int NTILE = 528; // 32*33/2 triangular 128x128 tiles
constexpr int PW = 32;     // partials slots per row (direct g + mirror rt, disjoint)

// ---------------------------------------------------------------------------
// ws layout:
//   Xb8      : fp8 e4m3 [4096][512]  @ 0          (2 MiB)  [dead after k_main]
//   cls      : int32[4096]           @ 2Mi        (16 KiB)
//   partials : float4 [32][4096]     @ 2Mi+16Ki   (2 MiB)  {S,P,E,W} TRANSPOSED
//   blockSums: float[16]             @ 0          (aliases dead Xb8; stream-safe)
// ---------------------------------------------------------------------------

// blocks 0..1023: fp32 -> fp8 e4m3 convert (8 elems/thread). block 1024: cls.
__global__ void k_convert(const float* __restrict__ X, uint32_t* __restrict__ Xb8,
                          const int* __restrict__ tbuf, int* __restrict__ cls) {
    if (blockIdx.x == 1024) {
        __shared__ int is64;
        const int t = threadIdx.x;          // 256 threads
        if (t == 0) is64 = 1;
        __syncthreads();
        // int64 targets => odd int32 words zero; inspect first 1024 words (OOB-safe)
        if (tbuf[4 * t + 1] != 0 || tbuf[4 * t + 3] != 0) is64 = 0;
        __syncthreads();
        const int f = is64;
#pragma unroll
        for (int q = 0; q < 4; ++q) {
            const int ti = 4 * t + q;
            const int v = tbuf[f ? 2 * ti : ti];
            cls[4 * ti + 0] = v; cls[4 * ti + 1] = v;
            cls[4 * ti + 2] = v; cls[4 * ti + 3] = v;
        }
        return;
    }
    const int idx = blockIdx.x * blockDim.x + threadIdx.x;   // 262144 threads
    const float4* s = (const float4*)X;
    float4 a = s[2 * idx + 0];
    float4 b = s[2 * idx + 1];
    uint32_t lo = 0, hi = 0;
    lo = __builtin_amdgcn_cvt_pk_fp8_f32(a.x, a.y, lo, 0);   // bytes 0,1
    lo = __builtin_amdgcn_cvt_pk_fp8_f32(a.z, a.w, lo, 1);   // bytes 2,3
    hi = __builtin_amdgcn_cvt_pk_fp8_f32(b.x, b.y, hi, 0);
    hi = __builtin_amdgcn_cvt_pk_fp8_f32(b.z, b.w, hi, 1);
    Xb8[2 * idx + 0] = lo;
    Xb8[2 * idx + 1] = hi;
}

// Triangular 128x128-tile fused GEMM+stats (rt >= g), fp8 e4m3 MFMA.
// 256 thr = 4 waves (2x2), wave = 64x64 (acc[4][4]). BK=64, 8 K-steps;
// 3-buf counted-vmcnt pipeline (R9-verified ordering). 16B-chunk XOR swizzle
// both-sides. LDS 48KB bufs -> 3 blocks/CU, all 528 blocks co-resident.
__launch_bounds__(256, 3)
__global__ void k_main(const char* __restrict__ Xb, const int* __restrict__ cls,
                       float* __restrict__ partials) {
    __shared__ __align__(16) char smem[3][16384];   // buf: 256 rows x 64B (A:128,B:128)
    __shared__ int rowcls[128], colcls[128];
    float4* accR = (float4*)&smem[0][0];   // [2][128] row stats (epilogue alias)
    float4* accC = (float4*)&smem[1][0];   // [2][128] col stats (epilogue alias)

    const int tid  = threadIdx.x;
    const int lane = tid & 63;
    const int wid  = tid >> 6;          // 0..3
    const int wr   = wid >> 1;          // 0..1 : rows wr*64..+63
    const int wc   = wid & 1;           // 0..1 : cols wc*64..+63
    const int rA   = lane & 15;
    const int kgrp = lane >> 4;

    // XCD-aware bijective swizzle (528 = 8*66); triangular decode rt >= g
    const int bid = (blockIdx.x & 7) * 66 + (blockIdx.x >> 3);
    int rt = (int)((sqrtf(8.0f * (float)bid + 1.0f) - 1.0f) * 0.5f);
    while (((rt + 1) * (rt + 2)) / 2 <= bid) ++rt;
    while ((rt * (rt + 1)) / 2 > bid) --rt;
    const int g  = bid - (rt * (rt + 1)) / 2;
    const int i0 = rt * 128;
    const int j0 = g * 128;
    const bool offdiag = (rt != g);

    if (tid < 128) rowcls[tid] = cls[i0 + tid];
    else           colcls[tid - 128] = cls[j0 + (tid - 128)];
    __syncthreads();   // cls ready; drains cls vmcnt before pipeline starts

    // staging: per K-step 128 A-rows + 128 B-rows x 64B = 1024 x 16B chunks,
    // 4/thread. Linear LDS dest (l*16); source chunk pre-swizzled
    // csrc = (l&3) ^ (prow&3)  (involution; ds_read applies the same XOR).
    size_t gbase[4];
#pragma unroll
    for (int q = 0; q < 4; ++q) {
        const int l    = q * 256 + tid;
        const int prow = l >> 2;
        const int csrc = (l & 3) ^ (prow & 3);
        const int grow = (prow < 128) ? (i0 + prow) : (j0 + prow - 128);
        gbase[q] = (size_t)grow * DK + (size_t)(csrc * 16);
    }

#define STAGE(bslot, kt)                                                       \
    {                                                                          \
        char* dst = &smem[(bslot)][0];                                         \
        const size_t kb = (size_t)(kt) * 64;                                   \
        _Pragma("unroll")                                                      \
        for (int q = 0; q < 4; ++q) {                                          \
            __builtin_amdgcn_global_load_lds(                                  \
                (const GLOBAL_AS void*)(Xb + gbase[q] + kb),                   \
                (LDS_AS void*)(dst + q * 4096 + wid * 1024), 16, 0, 0);        \
        }                                                                      \
    }

    STAGE(0, 0);
    STAGE(1, 1);

    f32x4 acc[4][4] = {};

#pragma unroll
    for (int t = 0; t < 8; ++t) {
        // drain own stage-t loads (stage t+1's 4 stay in flight); barrier =>
        // all 4 waves' stage-t writes landed before any ds_read of buf t.
        if (t < 7) { asm volatile("s_waitcnt vmcnt(4)" ::: "memory"); }
        else       { asm volatile("s_waitcnt vmcnt(0)" ::: "memory"); }
        __builtin_amdgcn_s_barrier();
        asm volatile("" ::: "memory");
        if (t + 2 < 8) STAGE((t + 2) % 3, t + 2);   // overwrites buf (t-1): its
                                                    // reads retired pre-barrier
        const char* bp = &smem[t % 3][0];
#pragma unroll
        for (int kk = 0; kk < 2; ++kk) {
            // lane fragment: 8 fp8 bytes at row, byte kk*32 + kgrp*8
            // chunk c = kk*2 + (kgrp>>1), sub s = kgrp&1; read chunk c^(row&3)
            long af[4], bg[4];
            const int c  = kk * 2 + (kgrp >> 1);
            const int s8 = (kgrp & 1) * 8;
#pragma unroll
            for (int m = 0; m < 4; ++m) {
                const int pr = wr * 64 + m * 16 + rA;
                af[m] = *(const long*)(bp + pr * 64 + ((c ^ (pr & 3)) << 4) + s8);
            }
#pragma unroll
            for (int n = 0; n < 4; ++n) {
                const int pr = 128 + wc * 64 + n * 16 + rA;
                bg[n] = *(const long*)(bp + pr * 64 + ((c ^ (pr & 3)) << 4) + s8);
            }
            // swapped operands: D[j][i] => i on rA axis, j on kgrp*4+reg axis
#pragma unroll
            for (int m = 0; m < 4; ++m)
#pragma unroll
                for (int n = 0; n < 4; ++n)
                    acc[m][n] = __builtin_amdgcn_mfma_f32_16x16x32_fp8_fp8(
                        bg[n], af[m], acc[m][n], 0, 0, 0);
        }
    }
#undef STAGE

    __syncthreads();   // all reads of smem bufs done -> stats aliases safe

    // epilogue: p(i,j), i = wr*64+m*16+rA, j = wc*64+n*16+kgrp*4+r
    // part(i) = rA&3, part(j) = r   (all tile bases %4 == 0)
    const int pi = rA & 3;
    int ci[4];
#pragma unroll
    for (int m = 0; m < 4; ++m) ci[m] = rowcls[wr * 64 + m * 16 + rA];
    float rS[4] = {0.f, 0.f, 0.f, 0.f};
    float rP[4] = {0.f, 0.f, 0.f, 0.f};
    float rE[4] = {0.f, 0.f, 0.f, 0.f};
    float rW[4] = {0.f, 0.f, 0.f, 0.f};

#pragma unroll
    for (int n = 0; n < 4; ++n) {
#pragma unroll
        for (int r = 0; r < 4; ++r) {
            const int cj = colcls[wc * 64 + n * 16 + kgrp * 4 + r];
            float cS = 0.f, cP = 0.f, cE = 0.f, cW = 0.f;
#pragma unroll
            for (int m = 0; m < 4; ++m) {
                const float p  = acc[m][n][r];
                const float ep = __expf(p);
                const bool sc = (ci[m] == cj);
                const bool sp = (pi == r);
                if (!sc && !sp) { rS[m] += ep; cS += ep; }   // dadc
                const float w = (!sc && sp) ? 2.f : ((sc && !sp) ? 1.f : 0.f);
                rP[m] += w * p;  rE[m] += w * ep;  rW[m] += w;
                cP += w * p;     cE += w * ep;     cW += w;
            }
            if (offdiag) {   // reduce over i (rA axis, 16-lane groups)
#pragma unroll
                for (int off = 1; off < 16; off <<= 1) {
                    cS += __shfl_xor(cS, off);
                    cP += __shfl_xor(cP, off);
                    cE += __shfl_xor(cE, off);
                    cW += __shfl_xor(cW, off);
                }
                if (rA == 0)
                    accC[wr * 128 + wc * 64 + n * 16 + kgrp * 4 + r] =
                        make_float4(cS, cP, cE, cW);
            }
        }
    }
    // row stats: reduce over j (kgrp axis): 2 shfl steps
#pragma unroll
    for (int m = 0; m < 4; ++m) {
        float vS = rS[m], vP = rP[m], vE = rE[m], vW = rW[m];
        vS += __shfl_xor(vS, 16); vS += __shfl_xor(vS, 32);
        vP += __shfl_xor(vP, 16); vP += __shfl_xor(vP, 32);
        vE += __shfl_xor(vE, 16); vE += __shfl_xor(vE, 32);
        vW += __shfl_xor(vW, 16); vW += __shfl_xor(vW, 32);
        if (kgrp == 0) accR[wc * 128 + wr * 64 + m * 16 + rA] = make_float4(vS, vP, vE, vW);
    }

    __syncthreads();
    // TRANSPOSED partials [slot][row]: contiguous 2KB burst per write, lines
    // owned by a single tile/XCD (no RMW amplification, no cross-XCD bounce).
    if (tid < 128) {   // fixed-order sums => deterministic
        float4 a0 = accR[tid], a1 = accR[128 + tid];
        ((float4*)partials)[(size_t)g * N + i0 + tid] =
            make_float4(a0.x + a1.x, a0.y + a1.y, a0.z + a1.z, a0.w + a1.w);
    } else if (offdiag) {
        const int c = tid - 128;
        float4 c0 = accC[c], c1 = accC[128 + c];
        ((float4*)partials)[(size_t)rt * N + j0 + c] =
            make_float4(c0.x + c1.x, c0.y + c1.y, c0.z + c1.z, c0.w + c1.w);
    }
}

// 16 blocks x 256 threads; thread owns one row; 32 fully-coalesced strided
// passes over transposed partials (each row's 32 slots all written: direct
// g in [0,R], mirror rt in (R,31]).
__global__ void k_rowloss(const float* __restrict__ partials, float* __restrict__ blockSums) {
    __shared__ float red[256];
    const int tid = threadIdx.x;
    const int row = blockIdx.x * 256 + tid;
    const float4* p = (const float4*)partials;
    float S = 0.f, P = 0.f, E = 0.f, W = 0.f;
#pragma unroll
    for (int s = 0; s < PW; ++s) {
        float4 v = p[(size_t)s * N + row];
        S += v.x; P += v.y; E += v.z; W += v.w;
    }
    red[tid] = W * logf(S) - P + E / S;
    __syncthreads();
    for (int s = 128; s > 0; s >>= 1) {
        if (tid < s) red[tid] += red[tid + s];
        __syncthreads();
    }
    if (tid == 0) blockSums[blockIdx.x] = red[0];
}

__global__ void k_final2(const float* __restrict__ blockSums, float* __restrict__ out) {
    const int t = threadIdx.x;           // 64 threads
    float v = (t < 16) ? blockSums[t] : 0.f;
#pragma unroll
    for (int off = 1; off < 16; off <<= 1) v += __shfl_xor(v, off);
    if (t == 0) out[0] = v / (float)N;
}

extern "C" void kernel_launch(void* const* d_in, const int* in_sizes, int n_in,
                              void* d_out, int out_size, void* d_ws, size_t ws_size,
                              hipStream_t stream) {
    const float* X = (const float*)d_in[0];
    const int*   T = (const int*)d_in[1];
    float* out = (float*)d_out;

    char* ws = (char*)d_ws;
    char*     Xb8   = ws;
    int*      cls   = (int*)(ws + (size_t)2 * 1024 * 1024);
    float*    parts = (float*)(ws + (size_t)2 * 1024 * 1024 + 16 * 1024);
    float*    bsums = (float*)ws;   // aliases Xb8 (dead after k_main; stream-ordered)

    hipLaunchKernelGGL(k_convert, dim3(1025),  dim3(256), 0, stream,
                       X, (uint32_t*)Xb8, T, cls);
    hipLaunchKernelGGL(k_main,    dim3(NTILE), dim3(256), 0, stream, Xb8, cls, parts);
    hipLaunchKernelGGL(k_rowloss, dim3(16),    dim3(256), 0, stream, parts, bsums);
    hipLaunchKernelGGL(k_final2,  dim3(1),     dim3(64),  0, stream, bsums, out);
}

// Round 11
// 51.993 us; speedup vs baseline: 1.1791x; 1.1791x over previous
//
#include <hip/hip_runtime.h>
#include <stdint.h>

#define GLOBAL_AS __attribute__((address_space(1)))
#define LDS_AS    __attribute__((address_space(3)))

typedef __attribute__((ext_vector_type(8))) __bf16 bf16x8;
typedef __attribute__((ext_vector_type(4))) float  f32x4;

static_assert(sizeof(bf16x8) == 16, "bf16x8 must be 16B");

constexpr int N  = 4096;   // B*P rows
constexpr int DK = 512;    // feature dim
constexpr int NTILE = 528; // 32*33/2 triangular 128x128 tiles
constexpr int GRID_MAIN = 512;
constexpr int PW = 32;     // partials slots per row (direct g + mirror rt, disjoint)

// ---------------------------------------------------------------------------
// ws layout:
//   Xb       : bf16 [4096][512]   @ 0            (4 MiB)  [dead after k_main]
//   cls      : int32[4096]        @ 4Mi          (16 KiB)
//   ctr      : int32[64]          @ 4Mi+16Ki     (256 B)   work-steal counter
//   partials : float4 [32][4096]  @ 4Mi+16Ki+256 (2 MiB)  {S,P,E,W} TRANSPOSED
//   blockSums: float[16]          @ 0  (aliases dead Xb; same-stream safe)
// ---------------------------------------------------------------------------

// blocks 0..1023: fp32->bf16 convert. block 1024: build cls + init steal ctr.
__global__ void k_convert(const float* __restrict__ X, __bf16* __restrict__ Xb,
                          const int* __restrict__ tbuf, int* __restrict__ cls,
                          int* __restrict__ ctr) {
    if (blockIdx.x == 1024) {
        __shared__ int is64;
        const int t = threadIdx.x;          // 256 threads
        if (t == 0) { is64 = 1; ctr[0] = GRID_MAIN; }
        __syncthreads();
        // int64 targets => odd int32 words zero; inspect first 1024 words (OOB-safe)
        if (tbuf[4 * t + 1] != 0 || tbuf[4 * t + 3] != 0) is64 = 0;
        __syncthreads();
        const int f = is64;
#pragma unroll
        for (int q = 0; q < 4; ++q) {
            const int ti = 4 * t + q;
            const int v = tbuf[f ? 2 * ti : ti];
            cls[4 * ti + 0] = v; cls[4 * ti + 1] = v;
            cls[4 * ti + 2] = v; cls[4 * ti + 3] = v;
        }
        return;
    }
    int idx = blockIdx.x * blockDim.x + threadIdx.x;
    const float4* s = (const float4*)X;
    float4 a = s[2 * idx + 0];
    float4 b = s[2 * idx + 1];
    bf16x8 o;
    o[0] = (__bf16)a.x; o[1] = (__bf16)a.y; o[2] = (__bf16)a.z; o[3] = (__bf16)a.w;
    o[4] = (__bf16)b.x; o[5] = (__bf16)b.y; o[6] = (__bf16)b.z; o[7] = (__bf16)b.w;
    *(bf16x8*)(Xb + 8 * idx) = o;
}

// Triangular 128x128-tile fused GEMM+stats (rt >= g). 512 thr = 8 waves (2x4),
// wave = 64x32 output (acc[4][2], lean transient epilogue -> no spill, R5).
// BK=32, 16 K-steps; 3-buf counted-vmcnt pipeline (R9-verified ordering;
// vmcnt never 0 in-loop, no __syncthreads in K-loop). (pr>>1)&3 chunk swizzle
// both-sides (R9: 0 conflicts). Work-steal: grid 512 co-resident (2 blk/CU,
// 16 waves/CU), last 16 tiles stolen -> tail 2T -> ~1.03T.
__launch_bounds__(512, 4)
__global__ void k_main(const __bf16* __restrict__ Xb, const int* __restrict__ cls,
                       float* __restrict__ partials, int* __restrict__ ctr) {
    __shared__ __align__(16) char smem[3][16384];   // buf: 256 rows x 64B (A:128,B:128)
    __shared__ int rowcls[128], colcls[128];
    __shared__ int shsteal;
    float4* accR = (float4*)&smem[0][0];   // [4][128] row stats (epilogue alias, 8KB)
    float4* accC = (float4*)&smem[1][0];   // [2][128] col stats (epilogue alias, 4KB)

    const int tid  = threadIdx.x;
    const int lane = tid & 63;
    const int wid  = tid >> 6;          // 0..7
    const int wr   = wid >> 2;          // 0..1 : rows wr*64..+63
    const int wc   = wid & 3;           // 0..3 : cols wc*32..+31
    const int rA   = lane & 15;
    const int kgrp = lane >> 4;
    const char* xb = (const char*)Xb;

    // XCD-aware bijective map: blocks 0..511 -> tiles xcd*66 + 0..63;
    // stolen ids 512..527 -> tiles xcd*66 + {64,65}.
    int tile = (blockIdx.x & 7) * 66 + (blockIdx.x >> 3);

    for (;;) {
        // triangular decode: tile = rt*(rt+1)/2 + g, rt >= g
        int rt = (int)((sqrtf(8.0f * (float)tile + 1.0f) - 1.0f) * 0.5f);
        while (((rt + 1) * (rt + 2)) / 2 <= tile) ++rt;
        while ((rt * (rt + 1)) / 2 > tile) --rt;
        const int g  = tile - (rt * (rt + 1)) / 2;
        const int i0 = rt * 128;
        const int j0 = g * 128;
        const bool offdiag = (rt != g);

        if (tid < 128)      rowcls[tid] = cls[i0 + tid];
        else if (tid < 256) colcls[tid - 128] = cls[j0 + (tid - 128)];
        __syncthreads();   // cls ready; prev tile done with aliased smem; vmcnt drained

        // staging: per K-step 256 rows x 64B = 1024 x 16B chunks, 2/thread.
        // Linear LDS dest (l*16); source chunk pre-swizzled
        // csrc = (l&3) ^ ((prow>>1)&3)  (involution; ds_read applies same XOR).
        size_t gbase[2];
#pragma unroll
        for (int q = 0; q < 2; ++q) {
            const int l    = q * 512 + tid;
            const int prow = l >> 2;
            const int csrc = (l & 3) ^ ((prow >> 1) & 3);
            const int grow = (prow < 128) ? (i0 + prow) : (j0 + prow - 128);
            gbase[q] = (size_t)grow * 1024 + (size_t)(csrc * 16);
        }

#define STAGE(bslot, kt)                                                       \
        {                                                                      \
            char* dst = &smem[(bslot)][0];                                     \
            const size_t kb = (size_t)(kt) * 64;                               \
            _Pragma("unroll")                                                  \
            for (int q = 0; q < 2; ++q) {                                      \
                __builtin_amdgcn_global_load_lds(                              \
                    (const GLOBAL_AS void*)(xb + gbase[q] + kb),               \
                    (LDS_AS void*)(dst + q * 8192 + tid * 16), 16, 0, 0);      \
            }                                                                  \
        }

        STAGE(0, 0);
        STAGE(1, 1);

        f32x4 acc[4][2] = {};

#pragma unroll
        for (int t = 0; t < 16; ++t) {
            // drain own stage-t loads (stage t+1's 2 stay in flight); barrier =>
            // all waves' stage-t writes landed before any ds_read of buf t.
            if (t < 15) { asm volatile("s_waitcnt vmcnt(2)" ::: "memory"); }
            else        { asm volatile("s_waitcnt vmcnt(0)" ::: "memory"); }
            __builtin_amdgcn_s_barrier();
            asm volatile("" ::: "memory");
            if (t + 2 < 16) STAGE((t + 2) % 3, t + 2);   // overwrites buf (t-1):
                                                         // reads retired pre-barrier
            const char* bp = &smem[t % 3][0];
            bf16x8 af[4], bg[2];
#pragma unroll
            for (int m = 0; m < 4; ++m) {
                const int pr = wr * 64 + m * 16 + rA;
                af[m] = *(const bf16x8*)(bp + pr * 64 + ((kgrp ^ ((pr >> 1) & 3)) << 4));
            }
#pragma unroll
            for (int n = 0; n < 2; ++n) {
                const int pr = 128 + wc * 32 + n * 16 + rA;   // B region rows 128..255
                bg[n] = *(const bf16x8*)(bp + pr * 64 + ((kgrp ^ ((pr >> 1) & 3)) << 4));
            }
            // swapped operands: D[j][i] => i on rA axis, j on kgrp*4+reg axis
#pragma unroll
            for (int m = 0; m < 4; ++m)
#pragma unroll
                for (int n = 0; n < 2; ++n)
                    acc[m][n] = __builtin_amdgcn_mfma_f32_16x16x32_bf16(bg[n], af[m],
                                                                        acc[m][n], 0, 0, 0);
        }
#undef STAGE

        __syncthreads();   // all reads of smem bufs done -> stats aliases safe

        // epilogue: p(i,j), i = wr*64+m*16+rA, j = wc*32+n*16+kgrp*4+r
        // part(i) = rA&3, part(j) = r   (all tile bases %4 == 0)
        const int pi = rA & 3;
        int ci[4];
#pragma unroll
        for (int m = 0; m < 4; ++m) ci[m] = rowcls[wr * 64 + m * 16 + rA];
        float rS[4] = {0.f, 0.f, 0.f, 0.f};
        float rP[4] = {0.f, 0.f, 0.f, 0.f};
        float rE[4] = {0.f, 0.f, 0.f, 0.f};
        float rW[4] = {0.f, 0.f, 0.f, 0.f};

#pragma unroll
        for (int n = 0; n < 2; ++n) {
#pragma unroll
            for (int r = 0; r < 4; ++r) {
                const int cj = colcls[wc * 32 + n * 16 + kgrp * 4 + r];
                float cS = 0.f, cP = 0.f, cE = 0.f, cW = 0.f;   // transient col stats
#pragma unroll
                for (int m = 0; m < 4; ++m) {
                    const float p  = acc[m][n][r];
                    const float ep = __expf(p);
                    const bool sc = (ci[m] == cj);
                    const bool sp = (pi == r);
                    if (!sc && !sp) { rS[m] += ep; cS += ep; }   // dadc
                    const float w = (!sc && sp) ? 2.f : ((sc && !sp) ? 1.f : 0.f);
                    rP[m] += w * p;  rE[m] += w * ep;  rW[m] += w;
                    cP += w * p;     cE += w * ep;     cW += w;
                }
                if (offdiag) {   // reduce over i (rA axis, 16-lane groups)
#pragma unroll
                    for (int off = 1; off < 16; off <<= 1) {
                        cS += __shfl_xor(cS, off);
                        cP += __shfl_xor(cP, off);
                        cE += __shfl_xor(cE, off);
                        cW += __shfl_xor(cW, off);
                    }
                    if (rA == 0)
                        accC[wr * 128 + wc * 32 + n * 16 + kgrp * 4 + r] =
                            make_float4(cS, cP, cE, cW);
                }
            }
        }
        // row stats: reduce over j (kgrp axis): 2 shfl steps
#pragma unroll
        for (int m = 0; m < 4; ++m) {
            float vS = rS[m], vP = rP[m], vE = rE[m], vW = rW[m];
            vS += __shfl_xor(vS, 16); vS += __shfl_xor(vS, 32);
            vP += __shfl_xor(vP, 16); vP += __shfl_xor(vP, 32);
            vE += __shfl_xor(vE, 16); vE += __shfl_xor(vE, 32);
            vW += __shfl_xor(vW, 16); vW += __shfl_xor(vW, 32);
            if (kgrp == 0)
                accR[wc * 128 + wr * 64 + m * 16 + rA] = make_float4(vS, vP, vE, vW);
        }

        __syncthreads();
        // TRANSPOSED partials [slot][row]: contiguous 2KB burst per write.
        if (tid < 128) {   // fixed-order sums => deterministic
            float4 a0 = accR[tid],       a1 = accR[128 + tid];
            float4 a2 = accR[256 + tid], a3 = accR[384 + tid];
            ((float4*)partials)[(size_t)g * N + i0 + tid] =
                make_float4(a0.x + a1.x + a2.x + a3.x, a0.y + a1.y + a2.y + a3.y,
                            a0.z + a1.z + a2.z + a3.z, a0.w + a1.w + a2.w + a3.w);
        } else if (tid < 256 && offdiag) {
            const int c = tid - 128;
            float4 c0 = accC[c], c1 = accC[128 + c];
            ((float4*)partials)[(size_t)rt * N + j0 + c] =
                make_float4(c0.x + c1.x, c0.y + c1.y, c0.z + c1.z, c0.w + c1.w);
        }

        // steal next tile (outputs are tile-determined => deterministic)
        if (tid == 0) shsteal = atomicAdd(ctr, 1);
        __syncthreads();
        const int t2 = shsteal;
        if (t2 >= NTILE) break;
        const int e = t2 - GRID_MAIN;                 // 0..15
        tile = (e >> 1) * 66 + 64 + (e & 1);          // remaining tiles xcd*66+{64,65}
    }
}

// 16 blocks x 256 threads; thread owns one row; 32 coalesced strided passes
// over transposed partials (all 32 slots of each row written: direct g in
// [0,R], mirror rt in (R,31]).
__global__ void k_rowloss(const float* __restrict__ partials, float* __restrict__ blockSums) {
    __shared__ float red[256];
    const int tid = threadIdx.x;
    const int row = blockIdx.x * 256 + tid;
    const float4* p = (const float4*)partials;
    float S = 0.f, P = 0.f, E = 0.f, W = 0.f;
#pragma unroll
    for (int s = 0; s < PW; ++s) {
        float4 v = p[(size_t)s * N + row];
        S += v.x; P += v.y; E += v.z; W += v.w;
    }
    red[tid] = W * logf(S) - P + E / S;
    __syncthreads();
    for (int s = 128; s > 0; s >>= 1) {
        if (tid < s) red[tid] += red[tid + s];
        __syncthreads();
    }
    if (tid == 0) blockSums[blockIdx.x] = red[0];
}

__global__ void k_final2(const float* __restrict__ blockSums, float* __restrict__ out) {
    const int t = threadIdx.x;           // 64 threads
    float v = (t < 16) ? blockSums[t] : 0.f;
#pragma unroll
    for (int off = 1; off < 16; off <<= 1) v += __shfl_xor(v, off);
    if (t == 0) out[0] = v / (float)N;
}

extern "C" void kernel_launch(void* const* d_in, const int* in_sizes, int n_in,
                              void* d_out, int out_size, void* d_ws, size_t ws_size,
                              hipStream_t stream) {
    const float* X = (const float*)d_in[0];
    const int*   T = (const int*)d_in[1];
    float* out = (float*)d_out;

    char* ws = (char*)d_ws;
    __bf16* Xb    = (__bf16*)ws;
    int*    cls   = (int*)(ws + (size_t)4 * 1024 * 1024);
    int*    ctr   = (int*)(ws + (size_t)4 * 1024 * 1024 + 16 * 1024);
    float*  parts = (float*)(ws + (size_t)4 * 1024 * 1024 + 16 * 1024 + 256);
    float*  bsums = (float*)ws;   // aliases Xb (dead after k_main; same-stream ordering)

    hipLaunchKernelGGL(k_convert, dim3(1025),      dim3(256), 0, stream, X, Xb, T, cls, ctr);
    hipLaunchKernelGGL(k_main,    dim3(GRID_MAIN), dim3(512), 0, stream, Xb, cls, parts, ctr);
    hipLaunchKernelGGL(k_rowloss, dim3(16),        dim3(256), 0, stream, parts, bsums);
    hipLaunchKernelGGL(k_final2,  dim3(1),         dim3(64),  0, stream, bsums, out);
}